// Round 16
// baseline (343.512 us; speedup 1.0000x reference)
//
#include <hip/hip_runtime.h>
#include <hip/hip_bf16.h>
#include <hip/hip_cooperative_groups.h>
#include <math.h>

namespace cg = cooperative_groups;

#define F_IN 512
#define H1   16
#define C2   40
#define BKL  6
#define BK   (1 << BKL)
#define NBMAX 2048
#define G    256
#define SEG  8
#define SEGLEN 32
#define TPAD 64

typedef __fp16 h2 __attribute__((ext_vector_type(2)));

__device__ __forceinline__ float bf2f(unsigned short u) {
  union { unsigned int i; float f; } v; v.i = ((unsigned int)u) << 16; return v.f;
}
__device__ __forceinline__ unsigned short f2bf(float f) {
  __hip_bfloat16 b = __float2bfloat16(f);
  return *reinterpret_cast<unsigned short*>(&b);
}
__device__ __forceinline__ float lo16(unsigned u) { return bf2f((unsigned short)(u & 0xffffu)); }
__device__ __forceinline__ float hi16(unsigned u) { return bf2f((unsigned short)(u >> 16)); }

// ================= fused CSR build: count -> scan -> fill -> sort =================
__global__ __launch_bounds__(1024) void k_build(const int* __restrict__ src,
                                                const int* __restrict__ dst,
                                                int* __restrict__ cnt,
                                                int* __restrict__ segtot,
                                                int* __restrict__ bstart,
                                                unsigned* __restrict__ ebuf,
                                                int* __restrict__ srt,
                                                int* __restrict__ sstart,
                                                int* __restrict__ scnt,
                                                float* __restrict__ dinv,
                                                unsigned short* g1bf,
                                                unsigned short* g2bf,
                                                int E, int NB, int epb, int QB, int N) {
  cg::grid_group grid = cg::this_grid();
  __shared__ int hh[NBMAX];
  __shared__ int sh[16][BK];
  __shared__ int sc[16][BK];
  __shared__ int stmp[1024];

  int g = blockIdx.x, t = threadIdx.x;
  int e0 = g * epb, e1 = min(e0 + epb, E);
  int n = e1 - e0;

  // ---- phase A: per-chunk bucket histogram ----
  for (int i = t; i < NB; i += 1024) hh[i] = 0;
  __syncthreads();
  if (n > 0) {
    int nv = n >> 2;
    const int4* dv = (const int4*)(dst + e0);
    for (int v = t; v < nv; v += 1024) {
      int4 d = dv[v];
      atomicAdd(&hh[d.x >> BKL], 1);
      atomicAdd(&hh[d.y >> BKL], 1);
      atomicAdd(&hh[d.z >> BKL], 1);
      atomicAdd(&hh[d.w >> BKL], 1);
    }
    for (int e = e0 + (nv << 2) + t; e < e1; e += 1024)
      atomicAdd(&hh[dst[e] >> BKL], 1);
  }
  __syncthreads();
  for (int i = t; i < NB; i += 1024) cnt[g * NB + i] = hh[i];

  grid.sync();

  // ---- phase B: segmented scan over g ----
  {
    int task = blockIdx.x * 16 + (t >> 6);
    int lane = t & 63;
    if (task < SEG * QB) {
      int s = task / QB, q = task - s * QB;
      int gs = lane >> 4, bs = lane & 15;
      int b = q * 16 + bs;
      bool ok = b < NB;
      int run = 0;
      int gbase = s * SEGLEN;
      for (int it = 0; it < SEGLEN; it += 4) {
        int gg = gbase + it + gs;
        int v = ok ? cnt[gg * NB + b] : 0;
        int incl = v;
        int n1 = __shfl_up(incl, 16, 64); if (lane >= 16) incl += n1;
        int n2 = __shfl_up(incl, 32, 64); if (lane >= 32) incl += n2;
        int ttot = __shfl(incl, 48 + bs, 64);
        if (ok) cnt[gg * NB + b] = run + incl - v;
        run += ttot;
      }
      if (gs == 0 && ok) segtot[s * NB + b] = run;
    }
  }

  grid.sync();

  // ---- phase C (block 0): segscan + padded bucket scan + tot + sentinel zrow ----
  if (blockIdx.x == 0) {
    for (int b = t; b < NB; b += 1024) {
      int run = 0;
#pragma unroll
      for (int s = 0; s < SEG; s++) {
        int v = segtot[s * NB + b];
        segtot[s * NB + b] = run;
        run += v;
      }
      scnt[(size_t)NB * BK + b] = run;   // real bucket total for phase E
    }
    __syncthreads();
    int b0 = t * 2;
    int v0 = 0, v1 = 0, s = 0;
    if (b0 < NB)     { v0 = (scnt[(size_t)NB * BK + b0]     + TPAD - 1) & ~(TPAD - 1); s += v0; }
    if (b0 + 1 < NB) { v1 = (scnt[(size_t)NB * BK + b0 + 1] + TPAD - 1) & ~(TPAD - 1); s += v1; }
    stmp[t] = s;
    __syncthreads();
    for (int off = 1; off < 1024; off <<= 1) {
      int add = (t >= off) ? stmp[t - off] : 0;
      __syncthreads();
      stmp[t] += add;
      __syncthreads();
    }
    int excl = stmp[t] - s;
    if (b0 < NB)     bstart[b0] = excl;
    if (b0 + 1 < NB) bstart[b0 + 1] = excl + v0;
    if (t == 1023)   bstart[NB] = excl + v0 + v1;
    if (t < H1) { g1bf[(size_t)N * H1 + t] = 0; g2bf[(size_t)N * H1 + t] = 0; }
  }

  grid.sync();

  // ---- phase D: fill ----
  {
    int s = g / SEGLEN;
    for (int i = t; i < NB; i += 1024)
      hh[i] = bstart[i] + segtot[s * NB + i] + cnt[g * NB + i];
    __syncthreads();
    if (n > 0) {
      int nv = n >> 2;
      const int4* dv = (const int4*)(dst + e0);
      const int4* sv = (const int4*)(src + e0);
      for (int v = t; v < nv; v += 1024) {
        int4 d = dv[v];
        int4 scv = sv[v];
        int p0 = atomicAdd(&hh[d.x >> BKL], 1);
        int p1 = atomicAdd(&hh[d.y >> BKL], 1);
        int p2 = atomicAdd(&hh[d.z >> BKL], 1);
        int p3 = atomicAdd(&hh[d.w >> BKL], 1);
        ebuf[p0] = ((unsigned)scv.x << BKL) | (unsigned)(d.x & (BK - 1));
        ebuf[p1] = ((unsigned)scv.y << BKL) | (unsigned)(d.y & (BK - 1));
        ebuf[p2] = ((unsigned)scv.z << BKL) | (unsigned)(d.z & (BK - 1));
        ebuf[p3] = ((unsigned)scv.w << BKL) | (unsigned)(d.w & (BK - 1));
      }
      for (int e = e0 + (nv << 2) + t; e < e1; e += 1024) {
        int d = dst[e];
        int pos = atomicAdd(&hh[d >> BKL], 1);
        ebuf[pos] = ((unsigned)src[e] << BKL) | (unsigned)(d & (BK - 1));
      }
    }
  }

  grid.sync();

  // ---- phase E: per-bucket counting sort (buckets strided across blocks) ----
  int w = t >> 6;
  for (int b = blockIdx.x; b < NB; b += gridDim.x) {
    __syncthreads();
    if (t < BK) {
#pragma unroll
      for (int ww = 0; ww < 16; ww++) sh[ww][t] = 0;
    }
    __syncthreads();
    int be0 = bstart[b];
    int tote = scnt[(size_t)NB * BK + b];
    int e1b = be0 + tote;
    int nv = tote >> 2;
    const uint4* ev = (const uint4*)(ebuf + be0);
    for (int v = t; v < nv; v += 1024) {
      uint4 p = ev[v];
      atomicAdd(&sh[w][p.x & (BK - 1)], 1);
      atomicAdd(&sh[w][p.y & (BK - 1)], 1);
      atomicAdd(&sh[w][p.z & (BK - 1)], 1);
      atomicAdd(&sh[w][p.w & (BK - 1)], 1);
    }
    for (int e = be0 + (nv << 2) + t; e < e1b; e += 1024)
      atomicAdd(&sh[w][ebuf[e] & (BK - 1)], 1);
    __syncthreads();
    if (t < BK) {
      int v = 0;
#pragma unroll
      for (int ww = 0; ww < 16; ww++) v += sh[ww][t];
      int inc = v;
#pragma unroll
      for (int off = 1; off < 64; off <<= 1) {
        int nn = __shfl_up(inc, off, 64);
        if (t >= off) inc += nn;
      }
      int excl = inc - v;
      scnt[b * BK + t] = v;
      sstart[b * BK + t] = be0 + excl;
      int node = b * BK + t;
      if (node < N) dinv[node] = rsqrtf((float)(v + 1));
      int base = excl;
#pragma unroll
      for (int ww = 0; ww < 16; ww++) { sc[ww][t] = base; base += sh[ww][t]; }
    }
    __syncthreads();
    for (int v = t; v < nv; v += 1024) {
      uint4 p = ev[v];
      int p0 = atomicAdd(&sc[w][p.x & (BK - 1)], 1);
      srt[be0 + p0] = (int)(p.x >> BKL);
      int p1 = atomicAdd(&sc[w][p.y & (BK - 1)], 1);
      srt[be0 + p1] = (int)(p.y >> BKL);
      int p2 = atomicAdd(&sc[w][p.z & (BK - 1)], 1);
      srt[be0 + p2] = (int)(p.z >> BKL);
      int p3 = atomicAdd(&sc[w][p.w & (BK - 1)], 1);
      srt[be0 + p3] = (int)(p.w >> BKL);
    }
    for (int e = be0 + (nv << 2) + t; e < e1b; e += 1024) {
      unsigned p = ebuf[e];
      int pos = atomicAdd(&sc[w][p & (BK - 1)], 1);
      srt[be0 + pos] = (int)(p >> BKL);
    }
  }
}

// ---------------- g1 = bf16( (x @ W1) * dinv[row] ), fp16 dot2, 2 rows/wave ----------------
__global__ __launch_bounds__(256, 3) void k_gemm1(const float* __restrict__ x,
                                                  const float* __restrict__ W1,
                                                  const float* __restrict__ dinv,
                                                  unsigned short* __restrict__ g1bf, int N) {
  int lane = threadIdx.x & 63;
  int wid = (int)((blockIdx.x * (long long)blockDim.x + threadIdx.x) >> 6);
  int nw = (gridDim.x * blockDim.x) >> 6;

  h2 wh[64];
#pragma unroll
  for (int p = 0; p < 4; p++) {
    const float* re = &W1[(lane * 8 + 2 * p) * H1];
    const float* ro = &W1[(lane * 8 + 2 * p + 1) * H1];
#pragma unroll
    for (int c = 0; c < 16; c++)
      wh[p * 16 + c] = __builtin_amdgcn_cvt_pkrtz(re[c], ro[c]);
  }

  int row = wid * 2;
  int step = nw * 2;
  float4 A0 = make_float4(0,0,0,0), A1 = A0, B0 = A0, B1 = A0;
  if (row < N) {
    const float4* xr = (const float4*)(x + (size_t)row * F_IN);
    A0 = xr[lane * 2]; A1 = xr[lane * 2 + 1];
    if (row + 1 < N) {
      const float4* xr2 = (const float4*)(x + (size_t)(row + 1) * F_IN);
      B0 = xr2[lane * 2]; B1 = xr2[lane * 2 + 1];
    }
  }
  while (row < N) {
    int nrow = row + step;
    float4 nA0 = make_float4(0,0,0,0), nA1 = nA0, nB0 = nA0, nB1 = nA0;
    if (nrow < N) {
      const float4* xr = (const float4*)(x + (size_t)nrow * F_IN);
      nA0 = xr[lane * 2]; nA1 = xr[lane * 2 + 1];
      if (nrow + 1 < N) {
        const float4* xr2 = (const float4*)(x + (size_t)(nrow + 1) * F_IN);
        nB0 = xr2[lane * 2]; nB1 = xr2[lane * 2 + 1];
      }
    }
    h2 xa0 = __builtin_amdgcn_cvt_pkrtz(A0.x, A0.y);
    h2 xa1 = __builtin_amdgcn_cvt_pkrtz(A0.z, A0.w);
    h2 xa2 = __builtin_amdgcn_cvt_pkrtz(A1.x, A1.y);
    h2 xa3 = __builtin_amdgcn_cvt_pkrtz(A1.z, A1.w);
    h2 xb0 = __builtin_amdgcn_cvt_pkrtz(B0.x, B0.y);
    h2 xb1 = __builtin_amdgcn_cvt_pkrtz(B0.z, B0.w);
    h2 xb2 = __builtin_amdgcn_cvt_pkrtz(B1.x, B1.y);
    h2 xb3 = __builtin_amdgcn_cvt_pkrtz(B1.z, B1.w);

    float accA[16], accB[16];
#pragma unroll
    for (int c = 0; c < 16; c++) { accA[c] = 0.f; accB[c] = 0.f; }
#pragma unroll
    for (int c = 0; c < 16; c++) {
      accA[c] = __builtin_amdgcn_fdot2(xa0, wh[c],      accA[c], false);
      accA[c] = __builtin_amdgcn_fdot2(xa1, wh[16 + c], accA[c], false);
      accA[c] = __builtin_amdgcn_fdot2(xa2, wh[32 + c], accA[c], false);
      accA[c] = __builtin_amdgcn_fdot2(xa3, wh[48 + c], accA[c], false);
      accB[c] = __builtin_amdgcn_fdot2(xb0, wh[c],      accB[c], false);
      accB[c] = __builtin_amdgcn_fdot2(xb1, wh[16 + c], accB[c], false);
      accB[c] = __builtin_amdgcn_fdot2(xb2, wh[32 + c], accB[c], false);
      accB[c] = __builtin_amdgcn_fdot2(xb3, wh[48 + c], accB[c], false);
    }

    float a8[8], b8[8];
#pragma unroll
    for (int i = 0; i < 8; i++) {
      float t0 = accA[2*i]   + __shfl_xor(accA[2*i],   1, 64);
      float t1 = accA[2*i+1] + __shfl_xor(accA[2*i+1], 1, 64);
      a8[i] = (lane & 1) ? t1 : t0;
      float s0 = accB[2*i]   + __shfl_xor(accB[2*i],   1, 64);
      float s1 = accB[2*i+1] + __shfl_xor(accB[2*i+1], 1, 64);
      b8[i] = (lane & 1) ? s1 : s0;
    }
    float a4[4], b4[4];
#pragma unroll
    for (int i = 0; i < 4; i++) {
      float t0 = a8[2*i]   + __shfl_xor(a8[2*i],   2, 64);
      float t1 = a8[2*i+1] + __shfl_xor(a8[2*i+1], 2, 64);
      a4[i] = ((lane >> 1) & 1) ? t1 : t0;
      float s0 = b8[2*i]   + __shfl_xor(b8[2*i],   2, 64);
      float s1 = b8[2*i+1] + __shfl_xor(b8[2*i+1], 2, 64);
      b4[i] = ((lane >> 1) & 1) ? s1 : s0;
    }
    float a2[2], b2v[2];
#pragma unroll
    for (int i = 0; i < 2; i++) {
      float t0 = a4[2*i]   + __shfl_xor(a4[2*i],   4, 64);
      float t1 = a4[2*i+1] + __shfl_xor(a4[2*i+1], 4, 64);
      a2[i] = ((lane >> 2) & 1) ? t1 : t0;
      float s0 = b4[2*i]   + __shfl_xor(b4[2*i],   4, 64);
      float s1 = b4[2*i+1] + __shfl_xor(b4[2*i+1], 4, 64);
      b2v[i] = ((lane >> 2) & 1) ? s1 : s0;
    }
    float ta0 = a2[0] + __shfl_xor(a2[0], 8, 64);
    float ta1 = a2[1] + __shfl_xor(a2[1], 8, 64);
    float va = ((lane >> 3) & 1) ? ta1 : ta0;
    float tb0 = b2v[0] + __shfl_xor(b2v[0], 8, 64);
    float tb1 = b2v[1] + __shfl_xor(b2v[1], 8, 64);
    float vb = ((lane >> 3) & 1) ? tb1 : tb0;
    va += __shfl_xor(va, 16, 64); va += __shfl_xor(va, 32, 64);
    vb += __shfl_xor(vb, 16, 64); vb += __shfl_xor(vb, 32, 64);

    if (lane < 16) {
      g1bf[(size_t)row * H1 + lane] = f2bf(va * dinv[row]);
      if (row + 1 < N) g1bf[(size_t)(row + 1) * H1 + lane] = f2bf(vb * dinv[row + 1]);
    }
    row = nrow; A0 = nA0; A1 = nA1; B0 = nB0; B1 = nB1;
  }
}

// ---------------- layer-1 aggregate ----------------
__global__ __launch_bounds__(256) void k_agg1(const int* __restrict__ srt,
                                              const int* __restrict__ sstart,
                                              const int* __restrict__ scnt,
                                              const unsigned short* __restrict__ g1bf,
                                              const float* __restrict__ dinv,
                                              const float* __restrict__ b1,
                                              unsigned short* __restrict__ g2bf, int N) {
  int t = threadIdx.x;
  int bb = blockIdx.x >> 1, half = blockIdx.x & 1;
  int slot = half * 32 + (t >> 3), L = t & 7;
  int node = bb * BK + slot;
  if (node >= N) return;
  int idx = bb * BK + slot;
  int s0 = sstart[idx];
  int end = s0 + scnt[idx];

  float acc[16];
#pragma unroll
  for (int k = 0; k < 16; k++) acc[k] = 0.f;

  const uint4* gp = (const uint4*)g1bf;
  for (int e = s0 + L; e < end; e += 32) {
    int i0 = srt[e];
    int i1 = (e + 8  < end) ? srt[e + 8]  : N;
    int i2 = (e + 16 < end) ? srt[e + 16] : N;
    int i3 = (e + 24 < end) ? srt[e + 24] : N;
    uint4 a0 = gp[(size_t)i0 * 2], a1 = gp[(size_t)i0 * 2 + 1];
    uint4 b0 = gp[(size_t)i1 * 2], b1v = gp[(size_t)i1 * 2 + 1];
    uint4 c0 = gp[(size_t)i2 * 2], c1 = gp[(size_t)i2 * 2 + 1];
    uint4 d0 = gp[(size_t)i3 * 2], d1 = gp[(size_t)i3 * 2 + 1];
    acc[0]  += lo16(a0.x)+lo16(b0.x)+lo16(c0.x)+lo16(d0.x);
    acc[1]  += hi16(a0.x)+hi16(b0.x)+hi16(c0.x)+hi16(d0.x);
    acc[2]  += lo16(a0.y)+lo16(b0.y)+lo16(c0.y)+lo16(d0.y);
    acc[3]  += hi16(a0.y)+hi16(b0.y)+hi16(c0.y)+hi16(d0.y);
    acc[4]  += lo16(a0.z)+lo16(b0.z)+lo16(c0.z)+lo16(d0.z);
    acc[5]  += hi16(a0.z)+hi16(b0.z)+hi16(c0.z)+hi16(d0.z);
    acc[6]  += lo16(a0.w)+lo16(b0.w)+lo16(c0.w)+lo16(d0.w);
    acc[7]  += hi16(a0.w)+hi16(b0.w)+hi16(c0.w)+hi16(d0.w);
    acc[8]  += lo16(a1.x)+lo16(b1v.x)+lo16(c1.x)+lo16(d1.x);
    acc[9]  += hi16(a1.x)+hi16(b1v.x)+hi16(c1.x)+hi16(d1.x);
    acc[10] += lo16(a1.y)+lo16(b1v.y)+lo16(c1.y)+lo16(d1.y);
    acc[11] += hi16(a1.y)+hi16(b1v.y)+hi16(c1.y)+hi16(d1.y);
    acc[12] += lo16(a1.z)+lo16(b1v.z)+lo16(c1.z)+lo16(d1.z);
    acc[13] += hi16(a1.z)+hi16(b1v.z)+hi16(c1.z)+hi16(d1.z);
    acc[14] += lo16(a1.w)+lo16(b1v.w)+lo16(c1.w)+lo16(d1.w);
    acc[15] += hi16(a1.w)+hi16(b1v.w)+hi16(c1.w)+hi16(d1.w);
  }

  float r8[8];
#pragma unroll
  for (int k = 0; k < 8; k++) {
    float a = acc[k]     + __shfl_xor(acc[k],     1, 64);
    float b = acc[8 + k] + __shfl_xor(acc[8 + k], 1, 64);
    r8[k] = (L & 1) ? b : a;
  }
  float r4[4];
#pragma unroll
  for (int k = 0; k < 4; k++) {
    float a = r8[k]     + __shfl_xor(r8[k],     2, 64);
    float b = r8[4 + k] + __shfl_xor(r8[4 + k], 2, 64);
    r4[k] = (L & 2) ? b : a;
  }
  float r2[2];
#pragma unroll
  for (int k = 0; k < 2; k++) {
    float a = r4[k]     + __shfl_xor(r4[k],     4, 64);
    float b = r4[2 + k] + __shfl_xor(r4[2 + k], 4, 64);
    r2[k] = (L & 4) ? b : a;
  }
  int fb = ((L & 1) << 3) | ((L & 2) << 1) | ((L & 4) >> 1);

  float di = dinv[node];
  unsigned sf = *(const unsigned*)(g1bf + (size_t)node * H1 + fb);
  float v0 = fmaxf(di * (r2[0] + lo16(sf)) + b1[fb],     0.f) * di;
  float v1 = fmaxf(di * (r2[1] + hi16(sf)) + b1[fb + 1], 0.f) * di;
  *(unsigned*)(g2bf + (size_t)node * H1 + fb) = (unsigned)f2bf(v0) | ((unsigned)f2bf(v1) << 16);
}

// ---------------- layer-2 aggregate + W2 matvec + log_softmax ----------------
__global__ __launch_bounds__(256) void k_agg2(const int* __restrict__ srt,
                                              const int* __restrict__ sstart,
                                              const int* __restrict__ scnt,
                                              const unsigned short* __restrict__ g2bf,
                                              const float* __restrict__ dinv,
                                              const float* __restrict__ W2,
                                              const float* __restrict__ b2,
                                              float* __restrict__ out, int N) {
  __shared__ float w2s[H1 * C2];
  __shared__ float b2s[C2];
  int t = threadIdx.x;
  for (int i = t; i < H1 * C2; i += 256) w2s[i] = W2[i];
  if (t < C2) b2s[t] = b2[t];
  __syncthreads();

  int bb = blockIdx.x >> 1, half = blockIdx.x & 1;
  int slot = half * 32 + (t >> 3), L = t & 7;
  int node = bb * BK + slot;
  if (node >= N) return;
  int idx = bb * BK + slot;
  int s0 = sstart[idx];
  int end = s0 + scnt[idx];

  float acc[16];
#pragma unroll
  for (int k = 0; k < 16; k++) acc[k] = 0.f;

  const uint4* gp = (const uint4*)g2bf;
  for (int e = s0 + L; e < end; e += 32) {
    int i0 = srt[e];
    int i1 = (e + 8  < end) ? srt[e + 8]  : N;
    int i2 = (e + 16 < end) ? srt[e + 16] : N;
    int i3 = (e + 24 < end) ? srt[e + 24] : N;
    uint4 a0 = gp[(size_t)i0 * 2], a1 = gp[(size_t)i0 * 2 + 1];
    uint4 b0 = gp[(size_t)i1 * 2], b1v = gp[(size_t)i1 * 2 + 1];
    uint4 c0 = gp[(size_t)i2 * 2], c1 = gp[(size_t)i2 * 2 + 1];
    uint4 d0 = gp[(size_t)i3 * 2], d1 = gp[(size_t)i3 * 2 + 1];
    acc[0]  += lo16(a0.x)+lo16(b0.x)+lo16(c0.x)+lo16(d0.x);
    acc[1]  += hi16(a0.x)+hi16(b0.x)+hi16(c0.x)+hi16(d0.x);
    acc[2]  += lo16(a0.y)+lo16(b0.y)+lo16(c0.y)+lo16(d0.y);
    acc[3]  += hi16(a0.y)+hi16(b0.y)+hi16(c0.y)+hi16(d0.y);
    acc[4]  += lo16(a0.z)+lo16(b0.z)+lo16(c0.z)+lo16(d0.z);
    acc[5]  += hi16(a0.z)+hi16(b0.z)+hi16(c0.z)+hi16(d0.z);
    acc[6]  += lo16(a0.w)+lo16(b0.w)+lo16(c0.w)+lo16(d0.w);
    acc[7]  += hi16(a0.w)+hi16(b0.w)+hi16(c0.w)+hi16(d0.w);
    acc[8]  += lo16(a1.x)+lo16(b1v.x)+lo16(c1.x)+lo16(d1.x);
    acc[9]  += hi16(a1.x)+hi16(b1v.x)+hi16(c1.x)+hi16(d1.x);
    acc[10] += lo16(a1.y)+lo16(b1v.y)+lo16(c1.y)+lo16(d1.y);
    acc[11] += hi16(a1.y)+hi16(b1v.y)+hi16(c1.y)+hi16(d1.y);
    acc[12] += lo16(a1.z)+lo16(b1v.z)+lo16(c1.z)+lo16(d1.z);
    acc[13] += hi16(a1.z)+hi16(b1v.z)+hi16(c1.z)+hi16(d1.z);
    acc[14] += lo16(a1.w)+lo16(b1v.w)+lo16(c1.w)+lo16(d1.w);
    acc[15] += hi16(a1.w)+hi16(b1v.w)+hi16(c1.w)+hi16(d1.w);
  }

  float r8[8];
#pragma unroll
  for (int k = 0; k < 8; k++) {
    float a = acc[k]     + __shfl_xor(acc[k],     1, 64);
    float b = acc[8 + k] + __shfl_xor(acc[8 + k], 1, 64);
    r8[k] = (L & 1) ? b : a;
  }
  float r4[4];
#pragma unroll
  for (int k = 0; k < 4; k++) {
    float a = r8[k]     + __shfl_xor(r8[k],     2, 64);
    float b = r8[4 + k] + __shfl_xor(r8[4 + k], 2, 64);
    r4[k] = (L & 2) ? b : a;
  }
  float r2[2];
#pragma unroll
  for (int k = 0; k < 2; k++) {
    float a = r4[k]     + __shfl_xor(r4[k],     4, 64);
    float b = r4[2 + k] + __shfl_xor(r4[2 + k], 4, 64);
    r2[k] = (L & 4) ? b : a;
  }
  int fb = ((L & 1) << 3) | ((L & 2) << 1) | ((L & 4) >> 1);

  float di = dinv[node];
  unsigned sf = *(const unsigned*)(g2bf + (size_t)node * H1 + fb);
  float sA = di * (r2[0] + lo16(sf));
  float sB = di * (r2[1] + hi16(sf));

  int lane = t & 63;
  int gbase = lane & ~7;
  float z[5];
#pragma unroll
  for (int k = 0; k < 5; k++) z[k] = b2s[L * 5 + k];
#pragma unroll
  for (int m = 0; m < 8; m++) {
    float a = __shfl(sA, gbase + m, 64);
    float b = __shfl(sB, gbase + m, 64);
    int j = ((m & 1) << 3) | ((m & 2) << 1) | ((m & 4) >> 1);
    const float* w0 = &w2s[j * C2 + L * 5];
    const float* w1 = &w2s[(j + 1) * C2 + L * 5];
#pragma unroll
    for (int k = 0; k < 5; k++) z[k] = fmaf(a, w0[k], fmaf(b, w1[k], z[k]));
  }
  float m5 = fmaxf(fmaxf(fmaxf(z[0], z[1]), fmaxf(z[2], z[3])), z[4]);
  m5 = fmaxf(m5, __shfl_xor(m5, 1, 64));
  m5 = fmaxf(m5, __shfl_xor(m5, 2, 64));
  m5 = fmaxf(m5, __shfl_xor(m5, 4, 64));
  float ssum = 0.f;
#pragma unroll
  for (int k = 0; k < 5; k++) ssum += expf(z[k] - m5);
  ssum += __shfl_xor(ssum, 1, 64);
  ssum += __shfl_xor(ssum, 2, 64);
  ssum += __shfl_xor(ssum, 4, 64);
  float lse = m5 + logf(ssum);
  float* op = out + (size_t)node * C2 + L * 5;
#pragma unroll
  for (int k = 0; k < 5; k++) op[k] = z[k] - lse;
}

extern "C" void kernel_launch(void* const* d_in, const int* in_sizes, int n_in,
                              void* d_out, int out_size, void* d_ws, size_t ws_size,
                              hipStream_t stream) {
  const float* x  = (const float*)d_in[0];
  const int*   ei = (const int*)d_in[1];
  const float* W1 = (const float*)d_in[2];
  const float* b1 = (const float*)d_in[3];
  const float* W2 = (const float*)d_in[4];
  const float* b2 = (const float*)d_in[5];
  float* out = (float*)d_out;

  int N = in_sizes[0] / F_IN;
  int E = in_sizes[1] / 2;
  const int* src = ei;
  const int* dst = ei + E;
  int NB = (N + BK - 1) / BK;
  int QB = (NB + 15) / 16;
  int epb = (((E + G - 1) / G) + 3) & ~3;

  char* w = (char*)d_ws;
  size_t off = 0;
  auto alloc = [&](size_t bytes) { char* p = w + off; off = (off + bytes + 255) & ~(size_t)255; return p; };
  int*   cnt    = (int*)alloc((size_t)G * NB * 4);
  int*   segtot = (int*)alloc((size_t)SEG * NB * 4);
  int*   bstart = (int*)alloc((size_t)(NB + 1) * 4);
  float* dinv   = (float*)alloc((size_t)N * 4);
  unsigned* ebuf = (unsigned*)alloc(((size_t)E + (size_t)NB * TPAD) * 4);
  int*   srt    = (int*)alloc(((size_t)E + (size_t)NB * TPAD) * 4);
  int*   sstart = (int*)alloc((size_t)NB * BK * 4);
  int*   scnt   = (int*)alloc(((size_t)NB * BK + NB) * 4);   // + NB tot slots
  unsigned short* g1bf = (unsigned short*)alloc((size_t)(N + 1) * H1 * 2);
  unsigned short* g2bf = (unsigned short*)alloc((size_t)(N + 1) * H1 * 2);

  void* args[] = {(void*)&src, (void*)&dst, (void*)&cnt, (void*)&segtot,
                  (void*)&bstart, (void*)&ebuf, (void*)&srt, (void*)&sstart,
                  (void*)&scnt, (void*)&dinv, (void*)&g1bf, (void*)&g2bf,
                  (void*)&E, (void*)&NB, (void*)&epb, (void*)&QB, (void*)&N};
  hipLaunchCooperativeKernel((void*)k_build, dim3(G), dim3(1024), args, 0, stream);
  k_gemm1 <<<1024, 256, 0, stream>>>(x, W1, dinv, g1bf, N);
  k_agg1  <<<NB * 2, 256, 0, stream>>>(srt, sstart, scnt, g1bf, dinv, b1, g2bf, N);
  k_agg2  <<<NB * 2, 256, 0, stream>>>(srt, sstart, scnt, g2bf, dinv, W2, b2, out, N);
}

// Round 17
// 205.512 us; speedup vs baseline: 1.6715x; 1.6715x over previous
//
#include <hip/hip_runtime.h>
#include <hip/hip_bf16.h>
#include <math.h>

#define F_IN 512
#define H1   16
#define C2   40
#define BKL  6                 // log2(nodes per bucket)
#define BK   (1 << BKL)        // 64 nodes per bucket
#define NBMAX 2048
#define G    256               // edge-chunk groups for count/fill
#define SEG  8                 // scan segments
#define SEGLEN 32              // G / SEG
#define TPAD 64                // bucket alignment only

typedef __fp16 h2 __attribute__((ext_vector_type(2)));

__device__ __forceinline__ float bf2f(unsigned short u) {
  union { unsigned int i; float f; } v; v.i = ((unsigned int)u) << 16; return v.f;
}
__device__ __forceinline__ unsigned short f2bf(float f) {
  __hip_bfloat16 b = __float2bfloat16(f);  // RNE
  return *reinterpret_cast<unsigned short*>(&b);
}
__device__ __forceinline__ float lo16(unsigned u) { return bf2f((unsigned short)(u & 0xffffu)); }
__device__ __forceinline__ float hi16(unsigned u) { return bf2f((unsigned short)(u >> 16)); }

// ---------------- phase 1: per-chunk bucket histogram (LDS atomics only) ----------------
__global__ __launch_bounds__(1024) void k_count(const int* __restrict__ dst,
                                                int* __restrict__ cnt,
                                                int E, int NB, int epb) {
  __shared__ int h[NBMAX];
  int g = blockIdx.x, t = threadIdx.x;
  for (int i = t; i < NB; i += 1024) h[i] = 0;
  __syncthreads();
  int e0 = g * epb, e1 = min(e0 + epb, E);
  for (int e = e0 + t; e < e1; e += 1024) atomicAdd(&h[dst[e] >> BKL], 1);
  __syncthreads();
  for (int i = t; i < NB; i += 1024) cnt[g * NB + i] = h[i];
}

// ---------------- phase 2a: segmented scan over g, wave per (segment, 16 buckets) ----------------
__global__ __launch_bounds__(256) void k_scan_seg(int* __restrict__ cnt,
                                                  int* __restrict__ segtot,
                                                  int NB, int QB) {
  int task = blockIdx.x * 4 + (threadIdx.x >> 6);
  int lane = threadIdx.x & 63;
  if (task >= SEG * QB) return;
  int s = task / QB, q = task - s * QB;
  int gs = lane >> 4, bs = lane & 15;
  int b = q * 16 + bs;
  bool ok = b < NB;
  int run = 0;
  int gbase = s * SEGLEN;
  for (int it = 0; it < SEGLEN; it += 4) {
    int g = gbase + it + gs;
    int v = ok ? cnt[g * NB + b] : 0;
    int incl = v;
    int n1 = __shfl_up(incl, 16, 64); if (lane >= 16) incl += n1;
    int n2 = __shfl_up(incl, 32, 64); if (lane >= 32) incl += n2;
    int ttot = __shfl(incl, 48 + bs, 64);
    if (ok) cnt[g * NB + b] = run + incl - v;
    run += ttot;
  }
  if (gs == 0 && ok) segtot[s * NB + b] = run;
}

// ---------------- phase 2b: per-bucket exclusive scan of segment totals (in place) + tot ----------------
__global__ __launch_bounds__(256) void k_segscan(int* __restrict__ segtot,
                                                 int* __restrict__ tot, int NB) {
  int b = blockIdx.x * 256 + threadIdx.x;
  if (b >= NB) return;
  int run = 0;
#pragma unroll
  for (int s = 0; s < SEG; s++) {
    int v = segtot[s * NB + b];
    segtot[s * NB + b] = run;
    run += v;
  }
  tot[b] = run;
}

// ---------------- phase 2c: exclusive scan of (aligned) bucket totals ----------------
__global__ __launch_bounds__(512) void k_scan_tot(const int* __restrict__ tot,
                                                  int* bstart, int NB) {
  __shared__ int lds[512];
  int t = threadIdx.x;
  int b0 = t * 4;
  int v[4];
  int s = 0;
#pragma unroll
  for (int k = 0; k < 4; k++) {
    int tv = (b0 + k < NB) ? tot[b0 + k] : 0;
    v[k] = (tv + TPAD - 1) & ~(TPAD - 1);
    s += v[k];
  }
  lds[t] = s;
  __syncthreads();
  for (int off = 1; off < 512; off <<= 1) {
    int add = (t >= off) ? lds[t - off] : 0;
    __syncthreads();
    lds[t] += add;
    __syncthreads();
  }
  int excl = lds[t] - s;
#pragma unroll
  for (int k = 0; k < 4; k++) {
    if (b0 + k < NB) bstart[b0 + k] = excl;
    excl += v[k];
  }
  if (t == 511) bstart[NB] = excl;
}

// ---------------- phase 3: fill (LDS cursors, private sub-ranges, no global atomics) ----------------
__global__ __launch_bounds__(1024) void k_fill(const int* __restrict__ src,
                                               const int* __restrict__ dst,
                                               const int* __restrict__ cnt,
                                               const int* __restrict__ segtot,
                                               const int* __restrict__ bstart,
                                               unsigned* __restrict__ ebuf,
                                               int E, int NB, int epb) {
  __shared__ int cur[NBMAX];
  int g = blockIdx.x, t = threadIdx.x;
  int s = g / SEGLEN;
  for (int i = t; i < NB; i += 1024)
    cur[i] = bstart[i] + segtot[s * NB + i] + cnt[g * NB + i];
  __syncthreads();
  int e0 = g * epb, e1 = min(e0 + epb, E);
  for (int e = e0 + t; e < e1; e += 1024) {
    int d = dst[e];
    int pos = atomicAdd(&cur[d >> BKL], 1);
    ebuf[pos] = ((unsigned)src[e] << BKL) | (unsigned)(d & (BK - 1));
  }
}

// ---------------- phase 4: per-bucket counting sort by dst slot ----------------
__global__ __launch_bounds__(256) void k_sort(const unsigned* __restrict__ ebuf,
                                              const int* __restrict__ bstart,
                                              const int* __restrict__ tot,
                                              int* __restrict__ srt,
                                              int* __restrict__ sstart,
                                              int* __restrict__ scnt,
                                              float* __restrict__ dinv, int N) {
  __shared__ int h[4][BK];
  __shared__ int cur[4][BK];
  __shared__ int stmp[BK];
  int b = blockIdx.x, t = threadIdx.x;
  int w = t >> 6;
  if (t < BK) { h[0][t] = 0; h[1][t] = 0; h[2][t] = 0; h[3][t] = 0; }
  __syncthreads();
  int e0 = bstart[b], e1 = e0 + tot[b];
  for (int e = e0 + t; e < e1; e += 256)
    atomicAdd(&h[w][ebuf[e] & (BK - 1)], 1);
  __syncthreads();
  if (t < BK) stmp[t] = h[0][t] + h[1][t] + h[2][t] + h[3][t];
  __syncthreads();
  if (t < BK) {  // wave 0 exactly: shuffle inclusive scan over 64 slots
    int v = stmp[t];
    int inc = v;
#pragma unroll
    for (int off = 1; off < 64; off <<= 1) {
      int n = __shfl_up(inc, off, 64);
      if (t >= off) inc += n;
    }
    int excl = inc - v;
    scnt[b * BK + t] = v;
    sstart[b * BK + t] = e0 + excl;
    int node = b * BK + t;
    if (node < N) dinv[node] = rsqrtf((float)(v + 1));
    int base = excl;
    cur[0][t] = base; base += h[0][t];
    cur[1][t] = base; base += h[1][t];
    cur[2][t] = base; base += h[2][t];
    cur[3][t] = base;
  }
  __syncthreads();
  for (int e = e0 + t; e < e1; e += 256) {
    unsigned p = ebuf[e];
    int pos = atomicAdd(&cur[w][p & (BK - 1)], 1);
    srt[e0 + pos] = (int)(p >> BKL);
  }
}

// ---------------- g1 = bf16( (x @ W1) * dinv[row] ), fp16 dot2, 2 rows/wave ----------------
__global__ __launch_bounds__(256, 3) void k_gemm1(const float* __restrict__ x,
                                                  const float* __restrict__ W1,
                                                  const float* __restrict__ dinv,
                                                  unsigned short* __restrict__ g1bf, int N) {
  int lane = threadIdx.x & 63;
  int wid = (int)((blockIdx.x * (long long)blockDim.x + threadIdx.x) >> 6);
  int nw = (gridDim.x * blockDim.x) >> 6;

  h2 wh[64];
#pragma unroll
  for (int p = 0; p < 4; p++) {
    const float* re = &W1[(lane * 8 + 2 * p) * H1];      // even k row
    const float* ro = &W1[(lane * 8 + 2 * p + 1) * H1];  // odd k row
#pragma unroll
    for (int c = 0; c < 16; c++)
      wh[p * 16 + c] = __builtin_amdgcn_cvt_pkrtz(re[c], ro[c]);
  }

  int row = wid * 2;
  int step = nw * 2;
  float4 A0 = make_float4(0,0,0,0), A1 = A0, B0 = A0, B1 = A0;
  if (row < N) {
    const float4* xr = (const float4*)(x + (size_t)row * F_IN);
    A0 = xr[lane * 2]; A1 = xr[lane * 2 + 1];
    if (row + 1 < N) {
      const float4* xr2 = (const float4*)(x + (size_t)(row + 1) * F_IN);
      B0 = xr2[lane * 2]; B1 = xr2[lane * 2 + 1];
    }
  }
  while (row < N) {
    int nrow = row + step;
    float4 nA0 = make_float4(0,0,0,0), nA1 = nA0, nB0 = nA0, nB1 = nA0;
    if (nrow < N) {
      const float4* xr = (const float4*)(x + (size_t)nrow * F_IN);
      nA0 = xr[lane * 2]; nA1 = xr[lane * 2 + 1];
      if (nrow + 1 < N) {
        const float4* xr2 = (const float4*)(x + (size_t)(nrow + 1) * F_IN);
        nB0 = xr2[lane * 2]; nB1 = xr2[lane * 2 + 1];
      }
    }
    h2 xa0 = __builtin_amdgcn_cvt_pkrtz(A0.x, A0.y);
    h2 xa1 = __builtin_amdgcn_cvt_pkrtz(A0.z, A0.w);
    h2 xa2 = __builtin_amdgcn_cvt_pkrtz(A1.x, A1.y);
    h2 xa3 = __builtin_amdgcn_cvt_pkrtz(A1.z, A1.w);
    h2 xb0 = __builtin_amdgcn_cvt_pkrtz(B0.x, B0.y);
    h2 xb1 = __builtin_amdgcn_cvt_pkrtz(B0.z, B0.w);
    h2 xb2 = __builtin_amdgcn_cvt_pkrtz(B1.x, B1.y);
    h2 xb3 = __builtin_amdgcn_cvt_pkrtz(B1.z, B1.w);

    float accA[16], accB[16];
#pragma unroll
    for (int c = 0; c < 16; c++) { accA[c] = 0.f; accB[c] = 0.f; }
#pragma unroll
    for (int c = 0; c < 16; c++) {
      accA[c] = __builtin_amdgcn_fdot2(xa0, wh[c],      accA[c], false);
      accA[c] = __builtin_amdgcn_fdot2(xa1, wh[16 + c], accA[c], false);
      accA[c] = __builtin_amdgcn_fdot2(xa2, wh[32 + c], accA[c], false);
      accA[c] = __builtin_amdgcn_fdot2(xa3, wh[48 + c], accA[c], false);
      accB[c] = __builtin_amdgcn_fdot2(xb0, wh[c],      accB[c], false);
      accB[c] = __builtin_amdgcn_fdot2(xb1, wh[16 + c], accB[c], false);
      accB[c] = __builtin_amdgcn_fdot2(xb2, wh[32 + c], accB[c], false);
      accB[c] = __builtin_amdgcn_fdot2(xb3, wh[48 + c], accB[c], false);
    }

    // two independent reduce-scatter butterflies
    float a8[8], b8[8];
#pragma unroll
    for (int i = 0; i < 8; i++) {
      float t0 = accA[2*i]   + __shfl_xor(accA[2*i],   1, 64);
      float t1 = accA[2*i+1] + __shfl_xor(accA[2*i+1], 1, 64);
      a8[i] = (lane & 1) ? t1 : t0;
      float s0 = accB[2*i]   + __shfl_xor(accB[2*i],   1, 64);
      float s1 = accB[2*i+1] + __shfl_xor(accB[2*i+1], 1, 64);
      b8[i] = (lane & 1) ? s1 : s0;
    }
    float a4[4], b4[4];
#pragma unroll
    for (int i = 0; i < 4; i++) {
      float t0 = a8[2*i]   + __shfl_xor(a8[2*i],   2, 64);
      float t1 = a8[2*i+1] + __shfl_xor(a8[2*i+1], 2, 64);
      a4[i] = ((lane >> 1) & 1) ? t1 : t0;
      float s0 = b8[2*i]   + __shfl_xor(b8[2*i],   2, 64);
      float s1 = b8[2*i+1] + __shfl_xor(b8[2*i+1], 2, 64);
      b4[i] = ((lane >> 1) & 1) ? s1 : s0;
    }
    float a2[2], b2v[2];
#pragma unroll
    for (int i = 0; i < 2; i++) {
      float t0 = a4[2*i]   + __shfl_xor(a4[2*i],   4, 64);
      float t1 = a4[2*i+1] + __shfl_xor(a4[2*i+1], 4, 64);
      a2[i] = ((lane >> 2) & 1) ? t1 : t0;
      float s0 = b4[2*i]   + __shfl_xor(b4[2*i],   4, 64);
      float s1 = b4[2*i+1] + __shfl_xor(b4[2*i+1], 4, 64);
      b2v[i] = ((lane >> 2) & 1) ? s1 : s0;
    }
    float ta0 = a2[0] + __shfl_xor(a2[0], 8, 64);
    float ta1 = a2[1] + __shfl_xor(a2[1], 8, 64);
    float va = ((lane >> 3) & 1) ? ta1 : ta0;
    float tb0 = b2v[0] + __shfl_xor(b2v[0], 8, 64);
    float tb1 = b2v[1] + __shfl_xor(b2v[1], 8, 64);
    float vb = ((lane >> 3) & 1) ? tb1 : tb0;
    va += __shfl_xor(va, 16, 64); va += __shfl_xor(va, 32, 64);
    vb += __shfl_xor(vb, 16, 64); vb += __shfl_xor(vb, 32, 64);

    if (lane < 16) {
      g1bf[(size_t)row * H1 + lane] = f2bf(va * dinv[row]);
      if (row + 1 < N) g1bf[(size_t)(row + 1) * H1 + lane] = f2bf(vb * dinv[row + 1]);
    }
    row = nrow; A0 = nA0; A1 = nA1; B0 = nB0; B1 = nB1;
  }
}

// ---------------- layer-1 aggregate: LDS-free, 8 lanes/node, guarded 2-deep pipeline ----------------
__global__ __launch_bounds__(256) void k_agg1(const int* __restrict__ srt,
                                              const int* __restrict__ sstart,
                                              const int* __restrict__ scnt,
                                              const unsigned short* __restrict__ g1bf,
                                              const float* __restrict__ dinv,
                                              const float* __restrict__ b1,
                                              unsigned short* __restrict__ g2bf, int N) {
  int t = threadIdx.x;
  int bb = blockIdx.x >> 1, half = blockIdx.x & 1;
  int slot = half * 32 + (t >> 3), L = t & 7;
  int node = bb * BK + slot;
  if (node >= N) return;
  int idx = bb * BK + slot;
  int s0 = sstart[idx];
  int end = s0 + scnt[idx];

  float acc[16];
#pragma unroll
  for (int k = 0; k < 16; k++) acc[k] = 0.f;

  int e = s0 + L;
  uint4 r0 = make_uint4(0,0,0,0), r1 = r0;
  if (e < end) {
    const uint4* row = (const uint4*)(g1bf + (size_t)srt[e] * H1);
    r0 = row[0]; r1 = row[1];
  }
  while (e < end) {
    int en = e + 8;
    uint4 n0 = make_uint4(0,0,0,0), n1 = n0;
    if (en < end) {
      const uint4* row = (const uint4*)(g1bf + (size_t)srt[en] * H1);
      n0 = row[0]; n1 = row[1];
    }
    acc[0]+=lo16(r0.x); acc[1]+=hi16(r0.x); acc[2]+=lo16(r0.y); acc[3]+=hi16(r0.y);
    acc[4]+=lo16(r0.z); acc[5]+=hi16(r0.z); acc[6]+=lo16(r0.w); acc[7]+=hi16(r0.w);
    acc[8]+=lo16(r1.x); acc[9]+=hi16(r1.x); acc[10]+=lo16(r1.y); acc[11]+=hi16(r1.y);
    acc[12]+=lo16(r1.z); acc[13]+=hi16(r1.z); acc[14]+=lo16(r1.w); acc[15]+=hi16(r1.w);
    r0 = n0; r1 = n1; e = en;
  }

  // 3-round reduce-scatter across the 8-lane group: lane keeps 2 features
  float r8[8];
#pragma unroll
  for (int k = 0; k < 8; k++) {
    float a = acc[k]     + __shfl_xor(acc[k],     1, 64);
    float b = acc[8 + k] + __shfl_xor(acc[8 + k], 1, 64);
    r8[k] = (L & 1) ? b : a;
  }
  float r4[4];
#pragma unroll
  for (int k = 0; k < 4; k++) {
    float a = r8[k]     + __shfl_xor(r8[k],     2, 64);
    float b = r8[4 + k] + __shfl_xor(r8[4 + k], 2, 64);
    r4[k] = (L & 2) ? b : a;
  }
  float r2[2];
#pragma unroll
  for (int k = 0; k < 2; k++) {
    float a = r4[k]     + __shfl_xor(r4[k],     4, 64);
    float b = r4[2 + k] + __shfl_xor(r4[2 + k], 4, 64);
    r2[k] = (L & 4) ? b : a;
  }
  int fb = ((L & 1) << 3) | ((L & 2) << 1) | ((L & 4) >> 1);  // even, bijective

  float di = dinv[node];
  unsigned sf = *(const unsigned*)(g1bf + (size_t)node * H1 + fb);
  float v0 = fmaxf(di * (r2[0] + lo16(sf)) + b1[fb],     0.f) * di;
  float v1 = fmaxf(di * (r2[1] + hi16(sf)) + b1[fb + 1], 0.f) * di;
  *(unsigned*)(g2bf + (size_t)node * H1 + fb) = (unsigned)f2bf(v0) | ((unsigned)f2bf(v1) << 16);
}

// ---------------- layer-2 aggregate + W2 matvec + log_softmax, fully fused ----------------
__global__ __launch_bounds__(256) void k_agg2(const int* __restrict__ srt,
                                              const int* __restrict__ sstart,
                                              const int* __restrict__ scnt,
                                              const unsigned short* __restrict__ g2bf,
                                              const float* __restrict__ dinv,
                                              const float* __restrict__ W2,
                                              const float* __restrict__ b2,
                                              float* __restrict__ out, int N) {
  __shared__ float w2s[H1 * C2];
  __shared__ float b2s[C2];
  int t = threadIdx.x;
  for (int i = t; i < H1 * C2; i += 256) w2s[i] = W2[i];
  if (t < C2) b2s[t] = b2[t];
  __syncthreads();

  int bb = blockIdx.x >> 1, half = blockIdx.x & 1;
  int slot = half * 32 + (t >> 3), L = t & 7;
  int node = bb * BK + slot;
  if (node >= N) return;
  int idx = bb * BK + slot;
  int s0 = sstart[idx];
  int end = s0 + scnt[idx];

  float acc[16];
#pragma unroll
  for (int k = 0; k < 16; k++) acc[k] = 0.f;

  int e = s0 + L;
  uint4 r0 = make_uint4(0,0,0,0), r1 = r0;
  if (e < end) {
    const uint4* row = (const uint4*)(g2bf + (size_t)srt[e] * H1);
    r0 = row[0]; r1 = row[1];
  }
  while (e < end) {
    int en = e + 8;
    uint4 n0 = make_uint4(0,0,0,0), n1 = n0;
    if (en < end) {
      const uint4* row = (const uint4*)(g2bf + (size_t)srt[en] * H1);
      n0 = row[0]; n1 = row[1];
    }
    acc[0]+=lo16(r0.x); acc[1]+=hi16(r0.x); acc[2]+=lo16(r0.y); acc[3]+=hi16(r0.y);
    acc[4]+=lo16(r0.z); acc[5]+=hi16(r0.z); acc[6]+=lo16(r0.w); acc[7]+=hi16(r0.w);
    acc[8]+=lo16(r1.x); acc[9]+=hi16(r1.x); acc[10]+=lo16(r1.y); acc[11]+=hi16(r1.y);
    acc[12]+=lo16(r1.z); acc[13]+=hi16(r1.z); acc[14]+=lo16(r1.w); acc[15]+=hi16(r1.w);
    r0 = n0; r1 = n1; e = en;
  }

  float r8[8];
#pragma unroll
  for (int k = 0; k < 8; k++) {
    float a = acc[k]     + __shfl_xor(acc[k],     1, 64);
    float b = acc[8 + k] + __shfl_xor(acc[8 + k], 1, 64);
    r8[k] = (L & 1) ? b : a;
  }
  float r4[4];
#pragma unroll
  for (int k = 0; k < 4; k++) {
    float a = r8[k]     + __shfl_xor(r8[k],     2, 64);
    float b = r8[4 + k] + __shfl_xor(r8[4 + k], 2, 64);
    r4[k] = (L & 2) ? b : a;
  }
  float r2[2];
#pragma unroll
  for (int k = 0; k < 2; k++) {
    float a = r4[k]     + __shfl_xor(r4[k],     4, 64);
    float b = r4[2 + k] + __shfl_xor(r4[2 + k], 4, 64);
    r2[k] = (L & 4) ? b : a;
  }
  int fb = ((L & 1) << 3) | ((L & 2) << 1) | ((L & 4) >> 1);

  float di = dinv[node];
  unsigned sf = *(const unsigned*)(g2bf + (size_t)node * H1 + fb);
  float sA = di * (r2[0] + lo16(sf));   // feature fb
  float sB = di * (r2[1] + hi16(sf));   // feature fb+1

  // fused W2 matvec: lane computes classes 5L..5L+4
  int lane = t & 63;
  int gbase = lane & ~7;
  float z[5];
#pragma unroll
  for (int k = 0; k < 5; k++) z[k] = b2s[L * 5 + k];
#pragma unroll
  for (int m = 0; m < 8; m++) {
    float a = __shfl(sA, gbase + m, 64);
    float b = __shfl(sB, gbase + m, 64);
    int j = ((m & 1) << 3) | ((m & 2) << 1) | ((m & 4) >> 1);  // fb(m)
    const float* w0 = &w2s[j * C2 + L * 5];
    const float* w1 = &w2s[(j + 1) * C2 + L * 5];
#pragma unroll
    for (int k = 0; k < 5; k++) z[k] = fmaf(a, w0[k], fmaf(b, w1[k], z[k]));
  }
  // group softmax over 40 classes (5 per lane x 8 lanes)
  float m5 = fmaxf(fmaxf(fmaxf(z[0], z[1]), fmaxf(z[2], z[3])), z[4]);
  m5 = fmaxf(m5, __shfl_xor(m5, 1, 64));
  m5 = fmaxf(m5, __shfl_xor(m5, 2, 64));
  m5 = fmaxf(m5, __shfl_xor(m5, 4, 64));
  float ssum = 0.f;
#pragma unroll
  for (int k = 0; k < 5; k++) ssum += expf(z[k] - m5);
  ssum += __shfl_xor(ssum, 1, 64);
  ssum += __shfl_xor(ssum, 2, 64);
  ssum += __shfl_xor(ssum, 4, 64);
  float lse = m5 + logf(ssum);
  float* op = out + (size_t)node * C2 + L * 5;
#pragma unroll
  for (int k = 0; k < 5; k++) op[k] = z[k] - lse;
}

extern "C" void kernel_launch(void* const* d_in, const int* in_sizes, int n_in,
                              void* d_out, int out_size, void* d_ws, size_t ws_size,
                              hipStream_t stream) {
  const float* x  = (const float*)d_in[0];
  const int*   ei = (const int*)d_in[1];
  const float* W1 = (const float*)d_in[2];
  const float* b1 = (const float*)d_in[3];
  const float* W2 = (const float*)d_in[4];
  const float* b2 = (const float*)d_in[5];
  float* out = (float*)d_out;

  int N = in_sizes[0] / F_IN;
  int E = in_sizes[1] / 2;
  const int* src = ei;
  const int* dst = ei + E;
  int NB = (N + BK - 1) / BK;     // 1563 for N=100000 (<= NBMAX)
  int QB = (NB + 15) / 16;        // bucket-groups of 16 for the segmented scan
  int epb = (E + G - 1) / G;      // edges per chunk group

  char* w = (char*)d_ws;
  size_t off = 0;
  auto alloc = [&](size_t bytes) { char* p = w + off; off = (off + bytes + 255) & ~(size_t)255; return p; };
  int*   cnt    = (int*)alloc((size_t)G * NB * 4);
  int*   segtot = (int*)alloc((size_t)SEG * NB * 4);
  int*   tot    = (int*)alloc((size_t)NB * 4);
  int*   bstart = (int*)alloc((size_t)(NB + 1) * 4);
  float* dinv   = (float*)alloc((size_t)N * 4);
  unsigned* ebuf = (unsigned*)alloc(((size_t)E + (size_t)NB * TPAD) * 4);
  int*   srt    = (int*)alloc(((size_t)E + (size_t)NB * TPAD) * 4);
  int*   sstart = (int*)alloc((size_t)NB * BK * 4);
  int*   scnt   = (int*)alloc((size_t)NB * BK * 4);
  unsigned short* g1bf = (unsigned short*)alloc((size_t)N * H1 * 2);
  unsigned short* g2bf = (unsigned short*)alloc((size_t)N * H1 * 2);

  k_count   <<<G, 1024, 0, stream>>>(dst, cnt, E, NB, epb);
  k_scan_seg<<<(SEG * QB + 3) / 4, 256, 0, stream>>>(cnt, segtot, NB, QB);
  k_segscan <<<(NB + 255) / 256, 256, 0, stream>>>(segtot, tot, NB);
  k_scan_tot<<<1, 512, 0, stream>>>(tot, bstart, NB);
  k_fill    <<<G, 1024, 0, stream>>>(src, dst, cnt, segtot, bstart, ebuf, E, NB, epb);
  k_sort    <<<NB, 256, 0, stream>>>(ebuf, bstart, tot, srt, sstart, scnt, dinv, N);
  k_gemm1   <<<1024, 256, 0, stream>>>(x, W1, dinv, g1bf, N);
  k_agg1    <<<NB * 2, 256, 0, stream>>>(srt, sstart, scnt, g1bf, dinv, b1, g2bf, N);
  k_agg2    <<<NB * 2, 256, 0, stream>>>(srt, sstart, scnt, g2bf, dinv, W2, b2, out, N);
}